// Round 19
// baseline (336.684 us; speedup 1.0000x reference)
//
#include <hip/hip_runtime.h>

#define HID 2048
#define HEADS 16
#define HD 128
#define BATCH 2
#define S 2048
#define ROWS (BATCH*S)

typedef short short8 __attribute__((ext_vector_type(8)));
typedef unsigned short ushort4v __attribute__((ext_vector_type(4)));
typedef unsigned short ushort2v __attribute__((ext_vector_type(2)));
typedef float f32x4 __attribute__((ext_vector_type(4)));
typedef float f32x16 __attribute__((ext_vector_type(16)));
typedef __bf16 bf16x8 __attribute__((ext_vector_type(8)));
typedef __bf16 bf16x4 __attribute__((ext_vector_type(4)));
typedef __bf16 bf16x2 __attribute__((ext_vector_type(2)));

static __device__ __forceinline__ float b2f(unsigned short u) {
  union { float f; unsigned int i; } v; v.i = ((unsigned int)u) << 16; return v.f;
}
static __device__ __forceinline__ unsigned short f2b(float f) {
  union { float f; unsigned int i; } v; v.f = f;
  unsigned int u = v.i;
  unsigned int r = ((u >> 16) & 1u) + 0x7fffu;
  return (unsigned short)((u + r) >> 16);
}

// async global->LDS, 16B per lane; LDS dest = wave-uniform base + lane*16 (global src is per-lane)
static __device__ __forceinline__ void gload_lds16(const unsigned short* g, unsigned short* l) {
  __builtin_amdgcn_global_load_lds(
      (const __attribute__((address_space(1))) unsigned int*)(const void*)g,
      (__attribute__((address_space(3))) unsigned int*)(void*)l,
      16, 0, 0);
}

// ---------------- debug fill (ws-size canary) ----------------
__global__ void fill_debug(unsigned short* __restrict__ out, long n) {
  long i = (long)blockIdx.x * blockDim.x + threadIdx.x;
  if (i < n) out[i] = 0x447A;  // bf16 1000.0
}

// ---- merged prep: conv repacks + x convert + rope tables + converts + 4x weight transpose ----
__global__ void prep_combined(const float* __restrict__ c1w, const float* __restrict__ c2w,
                              const float* __restrict__ x, const int* __restrict__ positions,
                              const float* __restrict__ c1b, const float* __restrict__ c2b,
                              const float* __restrict__ rmsw,
                              const float* __restrict__ wq, const float* __restrict__ wk,
                              const float* __restrict__ wv, const float* __restrict__ wo,
                              unsigned short* __restrict__ w1t0, unsigned short* __restrict__ w1t1,
                              unsigned short* __restrict__ w2t0, unsigned short* __restrict__ w2t1,
                              unsigned short* __restrict__ xb,
                              float* __restrict__ ctab, float* __restrict__ stab,
                              unsigned short* __restrict__ c1bb, unsigned short* __restrict__ c2bb,
                              unsigned short* __restrict__ rmswb, unsigned short* __restrict__ zpg,
                              unsigned short* __restrict__ wqkt, unsigned short* __restrict__ wvt,
                              unsigned short* __restrict__ wot) {
  int job = blockIdx.y;
  if (job == 0 || job == 1) {
    const float* w = (job == 0) ? c1w : c2w;
    unsigned short* o0 = (job == 0) ? w1t0 : w2t0;
    unsigned short* o1 = (job == 0) ? w1t1 : w2t1;
    long i = (long)blockIdx.x * 256 + threadIdx.x;
    f32x4 v = *(const f32x4*)(w + i*4);
    ushort2v a = { f2b(v[0]), f2b(v[2]) };
    ushort2v b = { f2b(v[1]), f2b(v[3]) };
    *(ushort2v*)(o0 + i*2) = a;
    *(ushort2v*)(o1 + i*2) = b;
  } else if (job == 2) {
    long i = (long)blockIdx.x * 256 + threadIdx.x;
    #pragma unroll
    for (int rep = 0; rep < 2; ++rep) {
      long idx = i + (long)rep * 1048576L;
      f32x4 v = *(const f32x4*)(x + idx*4);
      ushort4v o = { f2b(v[0]), f2b(v[1]), f2b(v[2]), f2b(v[3]) };
      *(ushort4v*)(xb + idx*4) = o;
    }
  } else if (job == 3) {
    int bx = blockIdx.x;
    if (bx < 512) {
      int t = bx * 4 + (threadIdx.x >> 6);
      int i = threadIdx.x & 63;
      float pos = (float)positions[t];
      float inv = powf(10000.0f, -(float)i / 64.0f);
      float ang = pos * inv;
      float sv, cv;
      sincosf(ang, &sv, &cv);
      ctab[t*64 + i] = cv;
      stab[t*64 + i] = sv;
    } else if (bx < 544) {
      int i = (bx - 512) * 256 + threadIdx.x;   // 0..8191
      if (i < 1024) c1bb[i] = f2b(c1b[i]);
      if (i < 2048) { c2bb[i] = f2b(c2b[i]); rmswb[i] = f2b(rmsw[i]); }
      zpg[i] = 0;                               // 8192-ushort zero page (kk-advancing reads)
    }
  } else {
    // ---- weight transpose fp32 [K,N] -> bf16 [N,K] (4 matrices) ----
    __shared__ unsigned short tl[64][73];
    int bx = blockIdx.x;
    int mat = bx >> 10;
    int tx = (bx >> 5) & 31, ty = bx & 31;
    const float* in; unsigned short* out; int perm;
    switch (mat) {
      case 0:  in = wq; out = wqkt;                       perm = 1; break;
      case 1:  in = wk; out = wqkt + (size_t)HID*HID;     perm = 1; break;
      case 2:  in = wv; out = wvt;                        perm = 0; break;
      default: in = wo; out = wot;                        perm = 0; break;
    }
    int n0 = tx * 64, k0 = ty * 64;
    int tid = threadIdx.x;
    int r = tid >> 3, c8 = (tid & 7) * 8;
    #pragma unroll
    for (int j = 0; j < 2; ++j) {
      int rr = r + j*32;
      const float* p = in + (size_t)(k0 + rr)*HID + n0 + c8;
      f32x4 v0 = *(const f32x4*)p;
      f32x4 v1 = *(const f32x4*)(p + 4);
      #pragma unroll
      for (int e = 0; e < 4; ++e) { tl[rr][c8 + e] = f2b(v0[e]); tl[rr][c8 + 4 + e] = f2b(v1[e]); }
    }
    __syncthreads();
    #pragma unroll
    for (int j = 0; j < 2; ++j) {
      int rr = r + j*32;
      int orow = n0 + rr;
      if (perm) {
        int s5 = (orow >> 5) & 3;
        s5 = (s5 == 1) ? 2 : (s5 == 2) ? 1 : s5;
        orow = (orow & ~127) | (s5 << 5) | (orow & 31);
      }
      short8 v;
      #pragma unroll
      for (int e = 0; e < 8; ++e) v[e] = (short)tl[c8 + e][rr];
      *(short8*)(out + (size_t)orow*HID + k0 + c8) = v;
    }
  }
}

// ============ shared GEMM helpers (swizzle proven: bank-conflict 0, rounds 2-18) ============

static __device__ __forceinline__ int swz_scol(int lane) {
  return (((lane & 7) * 16) ^ (((lane >> 3) & 7) << 4)) >> 1;   // swizzled src col (ushorts)
}

static __device__ __forceinline__ void rd_af(const unsigned short* Ah, bf16x8 (&afr)[4][2],
                                             int wm, int lr, int col0, int axor) {
  #pragma unroll
  for (int mi = 0; mi < 4; ++mi) {
    const unsigned short* rp = Ah + (wm*64 + mi*16 + lr) * 64;
    #pragma unroll
    for (int kk = 0; kk < 2; ++kk)
      afr[mi][kk] = *(const bf16x8*)(rp + (((kk*64 + col0) ^ axor) >> 1));
  }
}
static __device__ __forceinline__ void rd_bf(const unsigned short* Bh, bf16x8 (&bfr)[2][2],
                                             int wn, int lr, int col0, int axor) {
  #pragma unroll
  for (int ni = 0; ni < 2; ++ni) {
    const unsigned short* rp = Bh + (wn*32 + ni*16 + lr) * 64;
    #pragma unroll
    for (int kk = 0; kk < 2; ++kk)
      bfr[ni][kk] = *(const bf16x8*)(rp + (((kk*64 + col0) ^ axor) >> 1));
  }
}
static __device__ __forceinline__ void mfma16(const bf16x8 (&afr)[4][2], const bf16x8 (&bfr)[2][2],
                                              f32x4 (&ac)[4][2]) {
  #pragma unroll
  for (int kk = 0; kk < 2; ++kk)
    #pragma unroll
    for (int mi = 0; mi < 4; ++mi)
      #pragma unroll
      for (int ni = 0; ni < 2; ++ni)
        ac[mi][ni] = __builtin_amdgcn_mfma_f32_16x16x32_bf16(afr[mi][kk], bfr[ni][kk], ac[mi][ni], 0, 0, 0);
}

// ================= 128x256-tile GEMM, 3-deep pipeline (validated rounds 4-18; wo) =========

struct SPtrs { const unsigned short* p[6]; };

static __device__ __forceinline__ void build_ptrs(SPtrs& sp,
    const unsigned short* Ap, const unsigned short* Bp, int Ksz, int sh,
    int m0, int n0, const unsigned short* zpg, int tid) {
  int lane = tid & 63;
  int scol = swz_scol(lane);
  #pragma unroll
  for (int j = 0; j < 2; ++j) {
    int row = ((tid >> 6) * 2 + j) * 8 + (lane >> 3);               // 0..127
    int gr = m0 + row;
    sp.p[j]     = (sh && ((gr & (S - 1)) == 0)) ? (zpg + scol)
                                                : (Ap + (size_t)(gr - sh)*Ksz + scol);
    sp.p[2 + j] = Bp + (size_t)(n0 + row)*Ksz + scol;
    sp.p[4 + j] = Bp + (size_t)(n0 + 128 + row)*Ksz + scol;
  }
}

static __device__ __forceinline__ void stage6(unsigned short* buf, SPtrs& sp, int tid) {
  int c0 = (tid >> 6) * 1024;            // ushort offset of this wave's 2-chunk pair
  gload_lds16(sp.p[0], buf + c0);
  gload_lds16(sp.p[1], buf + c0 + 512);
  gload_lds16(sp.p[2], buf + 8192  + c0);
  gload_lds16(sp.p[3], buf + 8192  + c0 + 512);
  gload_lds16(sp.p[4], buf + 16384 + c0);
  gload_lds16(sp.p[5], buf + 16384 + c0 + 512);
  #pragma unroll
  for (int i = 0; i < 6; ++i) sp.p[i] += 64;
}

static __device__ __forceinline__ void gemm8_core(
    unsigned short* lds,
    const unsigned short* __restrict__ A1, const unsigned short* __restrict__ A2,
    const unsigned short* __restrict__ B1, const unsigned short* __restrict__ B2,
    int K1, int K2,
    const unsigned short* __restrict__ bias, const unsigned short* __restrict__ resid,
    void* __restrict__ Cout, int outmode, int N, int m0, int n0,
    int a1shift, const unsigned short* __restrict__ zrow) {
  int tid = threadIdx.x;
  int lane = tid & 63, w = tid >> 6;
  int wm = w >> 2, wn = w & 3;
  int lr = lane & 15, g = lane >> 4;
  int col0 = g * 16;
  int axor = (lr & 7) << 4;
  int nk1 = K1 >> 6;
  int nk = (K1 + K2) >> 6;
  f32x4 acc[2][4][2] = {};
  bf16x8 afr[4][2], bfr0[2][2], bfr1[2][2];

  unsigned short* buf0 = lds;            // each buf: A @0, B0 @8192, B1 @16384 (ushorts)
  unsigned short* buf1 = lds + 24576;
  unsigned short* buf2 = lds + 49152;

  SPtrs sp;
  build_ptrs(sp, A1, B1, K1, a1shift, m0, n0, zrow, tid);

  stage6(buf0, sp, tid);
  stage6(buf1, sp, tid);

  unsigned short* cur = buf0;
  unsigned short* nx1 = buf1;
  unsigned short* nx2 = buf2;
  for (int t = 0; t < nk; ++t) {
    if (t < nk - 1) asm volatile("s_waitcnt vmcnt(6)" ::: "memory");
    else            asm volatile("s_waitcnt vmcnt(0)" ::: "memory");
    __builtin_amdgcn_s_barrier();
    asm volatile("" ::: "memory");

    rd_af(cur,         afr,  wm, lr, col0, axor);
    rd_bf(cur + 8192,  bfr0, wn, lr, col0, axor);
    rd_bf(cur + 16384, bfr1, wn, lr, col0, axor);
    if (t + 2 < nk) {
      if (t + 2 == nk1) build_ptrs(sp, A2, B2, K2, 0, m0, n0, zrow, tid);
      stage6(nx2, sp, tid);
    }
    __builtin_amdgcn_s_setprio(1);
    mfma16(afr, bfr0, acc[0]);
    mfma16(afr, bfr1, acc[1]);
    __builtin_amdgcn_s_setprio(0);

    unsigned short* tmp = cur; cur = nx1; nx1 = nx2; nx2 = tmp;
  }

  #pragma unroll
  for (int qn = 0; qn < 2; ++qn)
    #pragma unroll
    for (int mi = 0; mi < 4; ++mi) {
      int row0 = m0 + wm*64 + mi*16 + g*4;
      #pragma unroll
      for (int ni = 0; ni < 2; ++ni) {
        int col = n0 + qn*128 + wn*32 + ni*16 + lr;
        float bv = bias ? b2f(bias[col]) : 0.f;
        f32x4 a = acc[qn][mi][ni];
        #pragma unroll
        for (int j = 0; j < 4; ++j) {
          size_t idx = (size_t)(row0 + j) * N + col;
          float v = a[j] + bv;
          if (resid) v += b2f(resid[idx]);
          if (outmode == 1) ((float*)Cout)[idx] = v;
          else ((unsigned short*)Cout)[idx] = f2b(v);
        }
      }
    }
}

template<int SHIFT>
__launch_bounds__(512, 1)
__global__ void gemm8_bt(const unsigned short* __restrict__ A1,
                         const unsigned short* __restrict__ A2,
                         const unsigned short* __restrict__ B1,
                         const unsigned short* __restrict__ B2,
                         int K1, int K2,
                         const unsigned short* __restrict__ bias,
                         const unsigned short* __restrict__ resid,
                         void* __restrict__ Cout, int outmode, int N,
                         const unsigned short* __restrict__ zrow) {
  __shared__ __align__(16) unsigned short lds[73728];   // 144 KiB, 3 bufs
  gemm8_core(lds, A1, A2, B1, B2, K1, K2, bias, resid, Cout, outmode, N,
             blockIdx.x*128, blockIdx.y*256, SHIFT, zrow);
}

// ============ 256x256-tile 4-phase core (validated rounds 12-18) ============
struct HPtr { const unsigned short* p0; const unsigned short* p1; };
static __device__ __forceinline__ void hinit(HPtr& h, const unsigned short* base,
                                             int row0, int Ksz, int tid) {
  int lane = tid & 63;
  int scol = swz_scol(lane);
  int r0 = ((tid >> 6) * 2) * 8 + (lane >> 3);
  h.p0 = base + (size_t)(row0 + r0) * Ksz + scol;
  h.p1 = base + (size_t)(row0 + r0 + 8) * Ksz + scol;
}
// shifted variant: reads row-1 (zero page at batch starts); zpg reads advance with kk
static __device__ __forceinline__ void hinit_sh(HPtr& h, const unsigned short* base,
                                                int row0, int Ksz,
                                                const unsigned short* zpg, int tid) {
  int lane = tid & 63;
  int scol = swz_scol(lane);
  int r0 = ((tid >> 6) * 2) * 8 + (lane >> 3);
  int g0 = row0 + r0, g1 = row0 + r0 + 8;
  h.p0 = ((g0 & (S - 1)) == 0) ? (zpg + scol) : (base + (size_t)(g0 - 1) * Ksz + scol);
  h.p1 = ((g1 & (S - 1)) == 0) ? (zpg + scol) : (base + (size_t)(g1 - 1) * Ksz + scol);
}
static __device__ __forceinline__ void hstage(unsigned short* slot, HPtr& h, int tid) {
  int c0 = (tid >> 6) * 1024;
  gload_lds16(h.p0, slot + c0);
  gload_lds16(h.p1, slot + c0 + 512);
  h.p0 += 64; h.p1 += 64;
}

// core K-loop (NKT 64-wide K-tiles), shared by qk / trio / duo
template<int NKT>
static __device__ __forceinline__ void gemm256_loop(
    unsigned short* lds, HPtr& hA0, HPtr& hA1, HPtr& hB0, HPtr& hB1,
    f32x4 (&acc)[2][2][4][2], int wm, int wn, int lr, int col0, int axor, int tid) {
  bf16x8 af[4][2], bf0[2][2], bf1[2][2];
  const int nk = NKT;
  // prologue: tile0 {A0,A1,B0,B1} -> buf0 ; tile1 {A0,B0,B1} -> buf1
  hstage(lds + 0,             hA0, tid);
  hstage(lds + 8192,          hA1, tid);
  hstage(lds + 16384,         hB0, tid);
  hstage(lds + 24576,         hB1, tid);
  hstage(lds + 32768 + 0,     hA0, tid);
  hstage(lds + 32768 + 16384, hB0, tid);
  hstage(lds + 32768 + 24576, hB1, tid);
  asm volatile("s_waitcnt vmcnt(6)" ::: "memory");   // tile0 landed; tile1's 3 halves in flight
  __builtin_amdgcn_s_barrier();
  asm volatile("" ::: "memory");

  for (int t = 0; t < nk; ++t) {
    unsigned short* cur = lds + (t & 1) * 32768;
    unsigned short* oth = lds + ((t & 1) ^ 1) * 32768;

    // ---- P1 (qm0,qn0): rd A0(8)+B0(4) ; stage A1(t+1) -> oth ----
    rd_af(cur,         af,  wm, lr, col0, axor);
    rd_bf(cur + 16384, bf0, wn, lr, col0, axor);
    if (t + 1 < nk) hstage(oth + 8192, hA1, tid);
    __builtin_amdgcn_s_barrier();
    asm volatile("s_waitcnt lgkmcnt(0)" ::: "memory");
    __builtin_amdgcn_s_setprio(1);
    mfma16(af, bf0, acc[0][0]);
    __builtin_amdgcn_s_setprio(0);
    __builtin_amdgcn_s_barrier();

    // ---- P2 (qm0,qn1): rd B1(4) (A regs reused) ; stage A0(t+2) -> cur ----
    rd_bf(cur + 24576, bf1, wn, lr, col0, axor);
    if (t + 2 < nk) hstage(cur, hA0, tid);
    __builtin_amdgcn_s_barrier();
    asm volatile("s_waitcnt lgkmcnt(0)" ::: "memory");
    __builtin_amdgcn_s_setprio(1);
    mfma16(af, bf1, acc[0][1]);
    __builtin_amdgcn_s_setprio(0);
    __builtin_amdgcn_s_barrier();

    // ---- P3 (qm1,qn1): rd A1(8) (B1 regs reused) ; stage B0(t+2) -> cur ----
    rd_af(cur + 8192, af, wm, lr, col0, axor);
    if (t + 2 < nk) hstage(cur + 16384, hB0, tid);
    __builtin_amdgcn_s_barrier();
    asm volatile("s_waitcnt lgkmcnt(0)" ::: "memory");
    __builtin_amdgcn_s_setprio(1);
    mfma16(af, bf1, acc[1][1]);
    __builtin_amdgcn_s_setprio(0);
    __builtin_amdgcn_s_barrier();

    // ---- P4 (qm1,qn0): all regs reused ; stage B1(t+2) -> cur ; counted vmcnt ----
    if (t + 2 < nk) hstage(cur + 24576, hB1, tid);
    __builtin_amdgcn_s_barrier();
    asm volatile("s_waitcnt lgkmcnt(0)" ::: "memory");
    __builtin_amdgcn_s_setprio(1);
    mfma16(af, bf0, acc[1][0]);
    __builtin_amdgcn_s_setprio(0);
    if (t + 2 < nk) asm volatile("s_waitcnt vmcnt(6)" ::: "memory");
    else            asm volatile("s_waitcnt vmcnt(0)" ::: "memory");
    __builtin_amdgcn_s_barrier();
    asm volatile("" ::: "memory");
  }
}

// ---- qk projection + FUSED RoPE (validated rounds 17-18) ----
__launch_bounds__(512, 1)
__global__ void gemm256_qk_rope(const unsigned short* __restrict__ A,
                                const unsigned short* __restrict__ B,
                                const float* __restrict__ ctab,
                                const float* __restrict__ stab,
                                unsigned short* __restrict__ qr,
                                unsigned short* __restrict__ kr) {
  __shared__ __align__(16) unsigned short lds[65536];   // 128 KiB
  int tid = threadIdx.x;
  int lane = tid & 63, w = tid >> 6;
  int wm = w >> 2, wn = w & 3;
  int lr = lane & 15, g = lane >> 4;
  int col0 = g * 16;
  int axor = (lr & 7) << 4;
  int nwg = gridDim.x * gridDim.y;
  int lin = blockIdx.y * gridDim.x + blockIdx.x;
  int cpx = nwg >> 3;
  int swz = (lin & 7) * cpx + (lin >> 3);
  int m0 = (swz % gridDim.x) * 256, n0 = (swz / gridDim.x) * 256;
  f32x4 acc[2][2][4][2] = {};           // [qm][qn][mi][ni]

  HPtr hA0, hA1, hB0, hB1;
  hinit(hA0, A, m0,       2048, tid);
  hinit(hA1, A, m0 + 128, 2048, tid);
  hinit(hB0, B, n0,       2048, tid);
  hinit(hB1, B, n0 + 128, 2048, tid);
  gemm256_loop<32>(lds, hA0, hA1, hB0, hB1, acc, wm, wn, lr, col0, axor, tid);

  // ---- fused RoPE epilogue ----
  float* L = (float*)lds;                // [128][132] f32 = 67.6KB
  const float SC = 0.08838834764831845f * 1.44269504088896340f;  // 1/sqrt(128) * log2(e)
  int h = n0 >> 8;
  int r2 = tid >> 2;                     // 0..127
  int ib = (tid & 3) * 16;               // i block 0/16/32/48
  #pragma unroll
  for (int qm = 0; qm < 2; ++qm) {
    #pragma unroll
    for (int qn = 0; qn < 2; ++qn) {
      #pragma unroll
      for (int mi = 0; mi < 4; ++mi)
        #pragma unroll
        for (int ni = 0; ni < 2; ++ni) {
          f32x4 a = acc[qm][qn][mi][ni];
          #pragma unroll
          for (int j = 0; j < 4; ++j)
            L[(wm*64 + mi*16 + g*4 + j)*132 + wn*32 + ni*16 + lr] = a[j];
        }
      __syncthreads();
      int rowg = m0 + qm*128 + r2;
      int t = rowg & (S - 1);
      size_t o = (size_t)rowg * HID + (size_t)h * HD;
      unsigned short* dst = (qn == 0) ? qr : kr;
      float sc = (qn == 0) ? SC : 1.0f;
      #pragma unroll
      for (int v4 = 0; v4 < 4; ++v4) {
        ushort4v w1, w2;
        #pragma unroll
        for (int e = 0; e < 4; ++e) {
          int i = ib + v4*4 + e;
          int pc = (i & 31) + ((i >> 5) << 6);
          float x1 = L[r2*132 + pc];
          float x2 = L[r2*132 + pc + 32];
          float cc = ctab[t*64 + i];
          float sn = stab[t*64 + i];
          w1[e] = f2b((x1*cc - x2*sn) * sc);
          w2[e] = f2b((x2*cc + x1*sn) * sc);
        }
        *(ushort4v*)(dst + o + ib + v4*4)      = w1;
        *(ushort4v*)(dst + o + 64 + ib + v4*4) = w2;
      }
      __syncthreads();
    }
  }
}

// ---- trio: conv1-pieceA (shifted) + conv1-pieceB + V-proj, uniform K=2048 ----
// (validated round 18: Vt epilogue via LDS transpose + s-coalesced writes)
__launch_bounds__(512, 1)
__global__ void gemm256_trio(const unsigned short* __restrict__ xb,
                             const unsigned short* __restrict__ w1t0,
                             const unsigned short* __restrict__ w1t1,
                             const unsigned short* __restrict__ wvt,
                             unsigned short* __restrict__ o1a,
                             unsigned short* __restrict__ o1b,
                             unsigned short* __restrict__ vtg,
                             const unsigned short* __restrict__ zpg) {
  __shared__ __align__(16) unsigned short lds[68608];
  int tid = threadIdx.x;
  int lane = tid & 63, w = tid >> 6;
  int wm = w >> 2, wn = w & 3;
  int lr = lane & 15, g = lane >> 4;
  int col0 = g * 16;
  int axor = (lr & 7) << 4;
  int lin = blockIdx.x;
  int swz = (lin & 7) * 32 + (lin >> 3);
  int job, s;
  if (swz < 64)       { job = 0; s = swz; }
  else if (swz < 128) { job = 1; s = swz - 64; }
  else                { job = 2; s = swz - 128; }
  int m0 = (s & 15) * 256;
  int n0 = (s >> 4) * 256;
  f32x4 acc[2][2][4][2] = {};

  HPtr hA0, hA1, hB0, hB1;
  if (job == 0) { hinit_sh(hA0, xb, m0, 2048, zpg, tid); hinit_sh(hA1, xb, m0 + 128, 2048, zpg, tid); }
  else          { hinit(hA0, xb, m0, 2048, tid);         hinit(hA1, xb, m0 + 128, 2048, tid); }
  const unsigned short* B = (job == 0) ? w1t0 : (job == 1) ? w1t1 : wvt;
  hinit(hB0, B, n0,       2048, tid);
  hinit(hB1, B, n0 + 128, 2048, tid);
  gemm256_loop<32>(lds, hA0, hA1, hB0, hB1, acc, wm, wn, lr, col0, axor, tid);

  if (job < 2) {
    unsigned short* C = (job == 0) ? o1a : o1b;   // bf16 [4096][1024] partial
    #pragma unroll
    for (int qm = 0; qm < 2; ++qm)
      #pragma unroll
      for (int mi = 0; mi < 4; ++mi) {
        int row0 = m0 + qm*128 + wm*64 + mi*16 + g*4;
        #pragma unroll
        for (int qn = 0; qn < 2; ++qn)
          #pragma unroll
          for (int ni = 0; ni < 2; ++ni) {
            int col = n0 + qn*128 + wn*32 + ni*16 + lr;
            f32x4 a = acc[qm][qn][mi][ni];
            #pragma unroll
            for (int j = 0; j < 4; ++j)
              C[(size_t)(row0 + j) * 1024 + col] = f2b(a[j]);
          }
      }
  } else {
    // ---- Vt epilogue: LDS transpose -> s-coalesced writes ----
    float* L = (float*)lds;               // [128][133] f32
    #pragma unroll
    for (int qm = 0; qm < 2; ++qm) {
      #pragma unroll
      for (int qn = 0; qn < 2; ++qn) {
        #pragma unroll
        for (int mi = 0; mi < 4; ++mi)
          #pragma unroll
          for (int ni = 0; ni < 2; ++ni) {
            f32x4 a = acc[qm][qn][mi][ni];
            #pragma unroll
            for (int j = 0; j < 4; ++j)
              L[(wm*64 + mi*16 + g*4 + j)*133 + wn*32 + ni*16 + lr] = a[j];
          }
        __syncthreads();
        int rowg0 = m0 + qm*128;          // quadrant s base (never straddles batch)
        int bb = rowg0 >> 11;
        int s0q = rowg0 & (S - 1);
        int dg0 = n0 + qn*128;            // quadrant d base
        #pragma unroll
        for (int cl = 0; cl < 16; ++cl) {
          int col = w*16 + cl;
          size_t vbase = ((size_t)bb * HID + dg0 + col) * S + s0q;
          vtg[vbase + lane]      = f2b(L[lane*133 + col]);
          vtg[vbase + 64 + lane] = f2b(L[(64 + lane)*133 + col]);
        }
        __syncthreads();
      }
    }
  }
}

// ---- duo: conv2-pieceA (shifted o1 @ W2_0) + conv2-pieceB (o1 @ W2_1), uniform K=1024 ----
__launch_bounds__(512, 1)
__global__ void gemm256_duo(const unsigned short* __restrict__ o1,
                            const unsigned short* __restrict__ w2t0,
                            const unsigned short* __restrict__ w2t1,
                            unsigned short* __restrict__ pA,
                            unsigned short* __restrict__ pB,
                            const unsigned short* __restrict__ zpg) {
  __shared__ __align__(16) unsigned short lds[65536];   // 128 KiB
  int tid = threadIdx.x;
  int lane = tid & 63, w = tid >> 6;
  int wm = w >> 2, wn = w & 3;
  int lr = lane & 15, g = lane >> 4;
  int col0 = g * 16;
  int axor = (lr & 7) << 4;
  int lin = blockIdx.x;
  int swz = (lin & 7) * 32 + (lin >> 3);
  int job = swz >> 7;                 // 0: shifted @ W2_0 ; 1: direct @ W2_1
  int s = swz & 127;
  int m0 = (s & 15) * 256;            // 16 M-tiles
  int n0 = (s >> 4) * 256;            // 8 N-tiles
  f32x4 acc[2][2][4][2] = {};

  HPtr hA0, hA1, hB0, hB1;
  if (job == 0) { hinit_sh(hA0, o1, m0, 1024, zpg, tid); hinit_sh(hA1, o1, m0 + 128, 1024, zpg, tid); }
  else          { hinit(hA0, o1, m0, 1024, tid);         hinit(hA1, o1, m0 + 128, 1024, tid); }
  const unsigned short* B = (job == 0) ? w2t0 : w2t1;
  hinit(hB0, B, n0,       1024, tid);
  hinit(hB1, B, n0 + 128, 1024, tid);
  gemm256_loop<16>(lds, hA0, hA1, hB0, hB1, acc, wm, wn, lr, col0, axor, tid);

  unsigned short* C = (job == 0) ? pA : pB;       // bf16 [4096][2048] partial
  #pragma unroll
  for (int qm = 0; qm < 2; ++qm)
    #pragma unroll
    for (int mi = 0; mi < 4; ++mi) {
      int row0 = m0 + qm*128 + wm*64 + mi*16 + g*4;
      #pragma unroll
      for (int qn = 0; qn < 2; ++qn)
        #pragma unroll
        for (int ni = 0; ni < 2; ++ni) {
          int col = n0 + qn*128 + wn*32 + ni*16 + lr;
          f32x4 a = acc[qm][qn][mi][ni];
          #pragma unroll
          for (int j = 0; j < 4; ++j)
            C[(size_t)(row0 + j) * HID + col] = f2b(a[j]);
        }
    }
}

// ---- o1 = o1a + o1b + bias (bf16, 4096x1024) ----
__global__ void add_bias(const unsigned short* __restrict__ a,
                         const unsigned short* __restrict__ b,
                         const unsigned short* __restrict__ bias,
                         unsigned short* __restrict__ o) {
  long i8 = ((long)blockIdx.x * 256 + threadIdx.x) * 8;   // over 4096*1024
  short8 va = *(const short8*)(a + i8);
  short8 vb = *(const short8*)(b + i8);
  short8 wb = *(const short8*)(bias + (i8 & 1023));
  short8 vo;
  #pragma unroll
  for (int e = 0; e < 8; ++e)
    vo[e] = (short)f2b(b2f((unsigned short)va[e]) + b2f((unsigned short)vb[e])
                       + b2f((unsigned short)wb[e]));
  *(short8*)(o + i8) = vo;
}

// ---- fused: hg = rmsnorm(pA + pB + bias + resid) * w ----
__global__ void rms_fuse(const unsigned short* __restrict__ pA,
                         const unsigned short* __restrict__ pB,
                         const unsigned short* __restrict__ bias,
                         const unsigned short* __restrict__ resid,
                         const unsigned short* __restrict__ w,
                         unsigned short* __restrict__ out) {
  int r = blockIdx.x;
  int c8 = threadIdx.x * 8;               // 256 threads x 8 = 2048
  size_t base = (size_t)r * HID + c8;
  short8 va = *(const short8*)(pA + base);
  short8 vb = *(const short8*)(pB + base);
  short8 vx = *(const short8*)(resid + base);
  short8 vbi = *(const short8*)(bias + c8);
  float f[8];
  float ss = 0.f;
  #pragma unroll
  for (int e = 0; e < 8; ++e) {
    f[e] = b2f((unsigned short)va[e]) + b2f((unsigned short)vb[e])
         + b2f((unsigned short)vbi[e]) + b2f((unsigned short)vx[e]);
    ss += f[e]*f[e];
  }
  #pragma unroll
  for (int o = 32; o; o >>= 1) ss += __shfl_xor(ss, o);
  __shared__ float red[4];
  if ((threadIdx.x & 63) == 0) red[threadIdx.x >> 6] = ss;
  __syncthreads();
  float tot = red[0] + red[1] + red[2] + red[3];
  float scale = rsqrtf(tot / (float)HID + 1e-6f);
  short8 wv = *(const short8*)(w + c8);
  short8 o8;
  #pragma unroll
  for (int e = 0; e < 8; ++e) o8[e] = (short)f2b(f[e] * scale * b2f((unsigned short)wv[e]));
  *(short8*)(out + base) = o8;
}

// ---------------- MFMA causal flash attention (32x32x16, in-register softmax, balanced pairs) ----
// Round-10-validated body (fixed causal guard, defer-max, xor-32 P-repack, DMA staging)
// + round-11-validated balanced pairing: block by does q-tiles (15-by) then (by) ->
// (2(15-by)+2)+(2by+2) = 36 KV-tiles for EVERY block; 256 blocks = exactly 2/CU, all
// resident, zero causal tail. 16 LDS b128 reads/tile (vs 34 in 16x16 kernel) — the
// round-18 recount shows LDS-read occupancy was the attn floor (~45us of 76).
#define KT 64

static __device__ __forceinline__ void attn32_pass(
    int qt, int b, int h, unsigned short* lds,
    const unsigned short* __restrict__ Qr, const unsigned short* __restrict__ Kr,
    const unsigned short* __restrict__ Vt, unsigned short* __restrict__ Out) {
  int tid = threadIdx.x, lane = tid & 63, w = tid >> 6;
  int q0w = qt * 128 + w * 32;
  size_t bS = (size_t)b * S;
  size_t ho = (size_t)h * HD;
  int l31 = lane & 31, hi = lane >> 5;
  int rsw = (lane & 7) << 3;                       // read-side swizzle (ushort units)
  __syncthreads();                                 // LDS reuse guard between passes
  // Q fragments (B-operand: col=q=l31, k=hi*8+e per 16-k step; 8 steps cover d=128)
  bf16x8 bq[8];
  {
    const unsigned short* qp = Qr + (bS + q0w + l31)*HID + ho + hi*8;
    #pragma unroll
    for (int kk = 0; kk < 8; ++kk) bq[kk] = *(const bf16x8*)(qp + kk*16);
  }
  // staging pointers (pre-swizzled source cols; advance per tile)
  const unsigned short* kp[4];
  const unsigned short* vp[4];
  #pragma unroll
  for (int j = 0; j < 4; ++j) {
    int c = w*4 + j;                       // chunk 0..15 (1KB each)
    int rk = c*4 + (lane >> 4);            // K row 0..63
    int sck = ((lane & 15) * 8) ^ ((rk & 7) << 3);
    kp[j] = Kr + (bS + rk)*HID + ho + sck;
    int rv = c*8 + (lane >> 3);            // V row (d) 0..127
    int scv = ((lane & 7) * 8) ^ ((rv & 7) << 3);
    vp[j] = Vt + ((size_t)b*HID + ho + rv)*S + scv;
  }
  int cdst = (w*4) * 512;                  // this wave's chunk-group dest (ushorts)
  unsigned short* curK = lds;
  unsigned short* curV = lds + 8192;
  unsigned short* nxtK = lds + 16384;
  unsigned short* nxtV = lds + 24576;
  #pragma unroll
  for (int j = 0; j < 4; ++j) {            // prologue: tile 0 -> cur
    gload_lds16(kp[j], curK + cdst + j*512);
    gload_lds16(vp[j], curV + cdst + j*512);
    kp[j] += (size_t)KT * HID;
    vp[j] += KT;
  }
  f32x16 o2[4] = {};               // O[q=crow(reg,hi)][d=ni*32+l31]
  float m = -1e30f, l = 0.f;
  int ntiles = 2*qt + 2;
  for (int kt = 0; kt < ntiles; ++kt) {
    // ---- single sync point: own DMA landed, then block-wide barrier ----
    asm volatile("s_waitcnt vmcnt(0)" ::: "memory");
    __builtin_amdgcn_s_barrier();
    asm volatile("" ::: "memory");
    if (kt + 1 < ntiles) {                 // issue next-tile DMA into the other buffer
      #pragma unroll
      for (int j = 0; j < 4; ++j) {
        gload_lds16(kp[j], nxtK + cdst + j*512);
        gload_lds16(vp[j], nxtV + cdst + j*512);
        kp[j] += (size_t)KT * HID;
        vp[j] += KT;
      }
    }
    // S^T = K·Q^T: A=K (row=key=mi*32+l31, k=hi*8+e), B=Q (col=q=l31)
    f32x16 st0 = {}, st1 = {};
    __builtin_amdgcn_s_setprio(1);
    #pragma unroll
    for (int kk = 0; kk < 8; ++kk) {
      bf16x8 a0 = *(const bf16x8*)(&curK[(l31)*128      + ((kk*16 + hi*8) ^ rsw)]);
      bf16x8 a1 = *(const bf16x8*)(&curK[(32 + l31)*128 + ((kk*16 + hi*8) ^ rsw)]);
      st0 = __builtin_amdgcn_mfma_f32_32x32x16_bf16(a0, bq[kk], st0, 0, 0, 0);
      st1 = __builtin_amdgcn_mfma_f32_32x32x16_bf16(a1, bq[kk], st1, 0, 0, 0);
    }
    __builtin_amdgcn_s_setprio(0);
    // ---- causal mask (tile max key > wave MIN q) + row max ----
    int kbase = kt * 64;
    float tm = -1e30f;
    if (kbase + 63 > q0w) {
      int qg = q0w + l31;
      #pragma unroll
      for (int r = 0; r < 16; ++r) {
        int crow = (r&3) + 8*(r>>2) + 4*hi;
        if (kbase + crow > qg)      st0[r] = -1e30f;
        if (kbase + 32 + crow > qg) st1[r] = -1e30f;
        tm = fmaxf(tm, fmaxf(st0[r], st1[r]));
      }
    } else {
      #pragma unroll
      for (int r = 0; r < 16; ++r) tm = fmaxf(tm, fmaxf(st0[r], st1[r]));
    }
    tm = fmaxf(tm, __shfl_xor(tm, 32));
    // ---- T13 defer-max rescale ----
    if (!__all(tm - m <= 11.5f)) {
      float mn = fmaxf(m, tm);
      float sc = exp2f(m - mn);
      #pragma unroll
      for (int r = 0; r < 16; ++r) {
        int crow = (r&3) + 8*(r>>2) + 4*hi;
        float scv = __shfl(sc, crow);      // lane crow holds sc for q=crow
        #pragma unroll
        for (int ni = 0; ni < 4; ++ni) o2[ni][r] *= scv;
      }
      l *= sc;
      m = mn;
    }
    // ---- exp + sum + pack to bf16 pairs (keys ascend within each u-word) ----
    float ts = 0.f;
    unsigned int u0[8], u1[8];
    #pragma unroll
    for (int j = 0; j < 8; ++j) {
      float a0 = exp2f(st0[2*j] - m), b0 = exp2f(st0[2*j+1] - m);
      float a1 = exp2f(st1[2*j] - m), b1 = exp2f(st1[2*j+1] - m);
      ts += a0 + b0 + a1 + b1;
      union { bf16x2 v; unsigned int ui; } p0, p1;
      p0.v = bf16x2{(__bf16)a0, (__bf16)b0};
      p1.v = bf16x2{(__bf16)a1, (__bf16)b1};
      u0[j] = p0.ui; u1[j] = p1.ui;
    }
    ts += __shfl_xor(ts, 32);
    l += ts;
    // ---- P->PV repack: ONE xor-32 exchange (partner lane has same q, other hi-half) ----
    unsigned int x0[8], x1[8];
    #pragma unroll
    for (int j = 0; j < 8; ++j) {
      x0[j] = (unsigned int)__shfl_xor((int)u0[j], 32);
      x1[j] = (unsigned int)__shfl_xor((int)u1[j], 32);
    }
    // ---- O += P @ V: A=P (row=q=l31, k=key s*16+hi*8+e), B=V (col=d=ni*32+l31) ----
    __builtin_amdgcn_s_setprio(1);
    #pragma unroll
    for (int s = 0; s < 4; ++s) {
      int j16 = s & 1;
      unsigned int w0, w1, w2, w3;
      if (s < 2) {     // mi = 0
        if (hi == 0) { w0=u0[4*j16];   w1=u0[4*j16+1]; w2=x0[4*j16];   w3=x0[4*j16+1]; }
        else         { w0=x0[4*j16+2]; w1=x0[4*j16+3]; w2=u0[4*j16+2]; w3=u0[4*j16+3]; }
      } else {         // mi = 1
        if (hi == 0) { w0=u1[4*j16];   w1=u1[4*j16+1]; w2=x1[4*j16];   w3=x1[4*j16+1]; }
        else         { w0=x1[4*j16+2]; w1=x1[4*j16+3]; w2=u1[4*j16+2]; w3=u1[4*j16+3]; }
      }
      union { unsigned int ui[4]; bf16x8 v; } pa;
      pa.ui[0]=w0; pa.ui[1]=w1; pa.ui[2]=w2; pa.ui[3]=w3;
      #pragma unroll
      for (int ni = 0; ni < 4; ++ni) {
        int d = ni*32 + l31;
        bf16x8 bv = *(const bf16x8*)(&curV[d*64 + ((s*16 + hi*8) ^ rsw)]);
        o2[ni] = __builtin_amdgcn_mfma_f32_32x32x16_bf16(pa.v, bv, o2[ni], 0, 0, 0);
      }
    }
    __builtin_amdgcn_s_setprio(0);
    unsigned short* t0 = curK; curK = nxtK; nxtK = t0;
    unsigned short* t1 = curV; curV = nxtV; nxtV = t1;
  }
  // ---- epilogue: per-q normalize (scalars live at lane q) ----
  float invl = 1.f / l;
  #pragma unroll
  for (int r = 0; r < 16; ++r) {
    int crow = (r&3) + 8*(r>>2) + 4*hi;
    float iv = __shfl(invl, crow);
    size_t rowbase = (bS + q0w + crow)*HID + ho + l31;
    #pragma unroll
    for (int ni = 0; ni < 4; ++ni)
      Out[rowbase + ni*32] = f2b(o2[ni][r] * iv);
  }
}

__launch_bounds__(256, 2)
__global__ void attn_mfma(const unsigned short* __restrict__ Qr,
                          const unsigned short* __restrict__ Kr,
                          const unsigned short* __restrict__ Vt,
                          unsigned short* __restrict__ Out) {
  // [0,8192) K0 | [8192,16384) V0 | [16384,24576) K1 | [24576,32768) V1 (ushorts, 64KB)
  __shared__ __align__(16) unsigned short lds[32768];
  int bh = blockIdx.x;
  int b = bh >> 4, h = bh & 15;
  int by = blockIdx.y;                       // 0..7
  attn32_pass(15 - by, b, h, lds, Qr, Kr, Vt, Out);   // heavy 128-q tile
  attn32_pass(by,      b, h, lds, Qr, Kr, Vt, Out);   // light tile; total = 36 KV-tiles/block
}

extern "C" void kernel_launch(void* const* d_in, const int* in_sizes, int n_in,
                              void* d_out, int out_size, void* d_ws, size_t ws_size,
                              hipStream_t stream) {
  const float* x_raw   = (const float*)d_in[0];
  const int* positions = (const int*)d_in[1];
  const float* wq_raw  = (const float*)d_in[2];
  const float* wk_raw  = (const float*)d_in[3];
  const float* wv_raw  = (const float*)d_in[4];
  const float* wo_raw  = (const float*)d_in[5];
  const float* c1w_raw = (const float*)d_in[6];
  const float* c1b_raw = (const float*)d_in[7];
  const float* c2w_raw = (const float*)d_in[8];
  const float* c2b_raw = (const float*)d_in[9];
  const float* rms_raw = (const float*)d_in[10];

  const size_t WS_NEEDED = 140000000;
  if (ws_size < WS_NEEDED) {
    long n = (long)out_size;
    fill_debug<<<dim3((unsigned)((n + 255) / 256)), dim3(256), 0, stream>>>((unsigned short*)d_out, n);
    return;
  }

  char* ws = (char*)d_ws;
  size_t off = 0;
  auto alloc = [&](size_t bytes) { char* p = ws + off; off += (bytes + 255) & ~(size_t)255; return p; };
  float* ctab          = (float*)alloc((size_t)S*64*4);
  float* stab          = (float*)alloc((size_t)S*64*4);
  unsigned short* wqkt = (unsigned short*)alloc((size_t)2*HID*HID*2);  // [wq^T ; wk^T], rope-permuted
  unsigned short* wvt  = (unsigned short*)alloc((size_t)HID*HID*2);
  unsigned short* wot  = (unsigned short*)alloc((size_t)HID*HID*2);
  unsigned short* w1t0 = (unsigned short*)alloc((size_t)1024*HID*2);
  unsigned short* w1t1 = (unsigned short*)alloc((size_t)1024*HID*2);
  unsigned short* w2t0 = (unsigned short*)alloc((size_t)HID*1024*2);
  unsigned short* w2t1 = (unsigned short*)alloc((size_t)HID*1024*2);
  unsigned short* xb   = (unsigned short*)alloc((size_t)ROWS*HID*2);   // resid for rms_fuse; reused as kr
  unsigned short* qrb  = (unsigned short*)alloc((size_t)ROWS*HID*2);   // q rotated
  unsigned short* o1   = (unsigned short*)alloc((size_t)ROWS*1024*2);
  unsigned short* yb   = (unsigned short*)alloc((size_t)ROWS*HID*2);   // attn out buffer
  unsigned short* hg   = (unsigned short*)alloc((size_t)ROWS*HID*2);
  unsigned short* qkf  = (unsigned short*)alloc((size_t)ROWS*2*HID*2); // partial scratch (trio/duo)
  unsigned short* vtg  = (unsigned short*)alloc((size_t)BATCH*HID*S*2);
  unsigned short* c1bb = (unsigned short*)alloc(1024*2);
  unsigned short* c2bb = (unsigned short*)alloc(2048*2);
  unsigned short* rmswb= (unsigned short*)alloc(2048*2);
  unsigned short* zpg  = (unsigned short*)alloc(8192*2);               // zero page (kk-advancing)
  unsigned short* krr  = xb;     // xb dead after rms_fuse (resid read)
  unsigned short* attn = yb;
  unsigned short* o1a  = qkf;                              // conv1 partials in qkf scratch
  unsigned short* o1b  = qkf + (size_t)ROWS*1024;
  unsigned short* cpA  = qkf;                              // conv2 partials (after add_bias)
  unsigned short* cpB  = qkf + (size_t)ROWS*HID;

  dim3 b256(256);
  dim3 b512(512);
  // merged prep: converts + rope tables + all 4 weight transposes in ONE dispatch
  prep_combined<<<dim3(4096, 5), b256, 0, stream>>>(
      c1w_raw, c2w_raw, x_raw, positions, c1b_raw, c2b_raw, rms_raw,
      wq_raw, wk_raw, wv_raw, wo_raw,
      w1t0, w1t1, w2t0, w2t1, xb, ctab, stab, c1bb, c2bb, rmswb, zpg,
      wqkt, wvt, wot);
  // trio (256^2 4-phase, 256 uniform K=2048 blocks): conv1-pieceA/B partials + V-proj
  gemm256_trio<<<dim3(256), b512, 0, stream>>>(xb, w1t0, w1t1, wvt, o1a, o1b, vtg, zpg);
  // o1 = o1a + o1b + bias
  add_bias<<<dim3(ROWS*1024/8/256), b256, 0, stream>>>(o1a, o1b, c1bb, o1);
  // duo (256^2 4-phase, 256 uniform K=1024 blocks): conv2 partials
  gemm256_duo<<<dim3(256), b512, 0, stream>>>(o1, w2t0, w2t1, cpA, cpB, zpg);
  // fused: hg = rmsnorm(pA + pB + b2 + xb) * rmsw
  rms_fuse<<<dim3(ROWS), b256, 0, stream>>>(cpA, cpB, c2bb, xb, rmswb, hg);
  // fused q|k projection + RoPE (256x256 4-phase + XCD swizzle): qrb/krr directly
  gemm256_qk_rope<<<dim3(ROWS/256, (2*HID)/256), b512, 0, stream>>>(hg, wqkt, ctab, stab, qrb, krr);
  // 32x32 balanced-pair attention: 256 blocks, 36 KV-tiles each, 2/CU all-resident
  attn_mfma<<<dim3(BATCH*HEADS, 8), b256, 0, stream>>>(qrb, krr, vtg, attn);
  // output projection: d_out = attn @ wo^T   [4096 x 2048], f32 out
  gemm8_bt<0><<<dim3(ROWS/128, HID/256), b512, 0, stream>>>(attn, attn, wot, wot, HID, 0, nullptr, nullptr, d_out, 1, HID, nullptr);
}

// Round 20
// 330.156 us; speedup vs baseline: 1.0198x; 1.0198x over previous
//
#include <hip/hip_runtime.h>

#define HID 2048
#define HEADS 16
#define HD 128
#define BATCH 2
#define S 2048
#define ROWS (BATCH*S)

typedef short short8 __attribute__((ext_vector_type(8)));
typedef unsigned short ushort4v __attribute__((ext_vector_type(4)));
typedef unsigned short ushort2v __attribute__((ext_vector_type(2)));
typedef float f32x4 __attribute__((ext_vector_type(4)));
typedef __bf16 bf16x8 __attribute__((ext_vector_type(8)));
typedef __bf16 bf16x4 __attribute__((ext_vector_type(4)));

static __device__ __forceinline__ float b2f(unsigned short u) {
  union { float f; unsigned int i; } v; v.i = ((unsigned int)u) << 16; return v.f;
}
static __device__ __forceinline__ unsigned short f2b(float f) {
  union { float f; unsigned int i; } v; v.f = f;
  unsigned int u = v.i;
  unsigned int r = ((u >> 16) & 1u) + 0x7fffu;
  return (unsigned short)((u + r) >> 16);
}

// async global->LDS, 16B per lane; LDS dest = wave-uniform base + lane*16 (global src is per-lane)
static __device__ __forceinline__ void gload_lds16(const unsigned short* g, unsigned short* l) {
  __builtin_amdgcn_global_load_lds(
      (const __attribute__((address_space(1))) unsigned int*)(const void*)g,
      (__attribute__((address_space(3))) unsigned int*)(void*)l,
      16, 0, 0);
}

// ---------------- debug fill (ws-size canary) ----------------
__global__ void fill_debug(unsigned short* __restrict__ out, long n) {
  long i = (long)blockIdx.x * blockDim.x + threadIdx.x;
  if (i < n) out[i] = 0x447A;  // bf16 1000.0
}

// ---- merged prep: conv repacks + x convert + rope tables + converts + 4x weight transpose ----
__global__ void prep_combined(const float* __restrict__ c1w, const float* __restrict__ c2w,
                              const float* __restrict__ x, const int* __restrict__ positions,
                              const float* __restrict__ c1b, const float* __restrict__ c2b,
                              const float* __restrict__ rmsw,
                              const float* __restrict__ wq, const float* __restrict__ wk,
                              const float* __restrict__ wv, const float* __restrict__ wo,
                              unsigned short* __restrict__ w1t0, unsigned short* __restrict__ w1t1,
                              unsigned short* __restrict__ w2t0, unsigned short* __restrict__ w2t1,
                              unsigned short* __restrict__ xb,
                              float* __restrict__ ctab, float* __restrict__ stab,
                              unsigned short* __restrict__ c1bb, unsigned short* __restrict__ c2bb,
                              unsigned short* __restrict__ rmswb, unsigned short* __restrict__ zpg,
                              unsigned short* __restrict__ wqkt, unsigned short* __restrict__ wvt,
                              unsigned short* __restrict__ wot) {
  int job = blockIdx.y;
  if (job == 0 || job == 1) {
    const float* w = (job == 0) ? c1w : c2w;
    unsigned short* o0 = (job == 0) ? w1t0 : w2t0;
    unsigned short* o1 = (job == 0) ? w1t1 : w2t1;
    long i = (long)blockIdx.x * 256 + threadIdx.x;
    f32x4 v = *(const f32x4*)(w + i*4);
    ushort2v a = { f2b(v[0]), f2b(v[2]) };
    ushort2v b = { f2b(v[1]), f2b(v[3]) };
    *(ushort2v*)(o0 + i*2) = a;
    *(ushort2v*)(o1 + i*2) = b;
  } else if (job == 2) {
    long i = (long)blockIdx.x * 256 + threadIdx.x;
    #pragma unroll
    for (int rep = 0; rep < 2; ++rep) {
      long idx = i + (long)rep * 1048576L;
      f32x4 v = *(const f32x4*)(x + idx*4);
      ushort4v o = { f2b(v[0]), f2b(v[1]), f2b(v[2]), f2b(v[3]) };
      *(ushort4v*)(xb + idx*4) = o;
    }
  } else if (job == 3) {
    int bx = blockIdx.x;
    if (bx < 512) {
      int t = bx * 4 + (threadIdx.x >> 6);
      int i = threadIdx.x & 63;
      float pos = (float)positions[t];
      float inv = powf(10000.0f, -(float)i / 64.0f);
      float ang = pos * inv;
      float sv, cv;
      sincosf(ang, &sv, &cv);
      ctab[t*64 + i] = cv;
      stab[t*64 + i] = sv;
    } else if (bx < 544) {
      int i = (bx - 512) * 256 + threadIdx.x;   // 0..8191
      if (i < 1024) c1bb[i] = f2b(c1b[i]);
      if (i < 2048) { c2bb[i] = f2b(c2b[i]); rmswb[i] = f2b(rmsw[i]); }
      zpg[i] = 0;                               // 8192-ushort zero page (kk-advancing reads)
    }
  } else {
    // ---- weight transpose fp32 [K,N] -> bf16 [N,K] (4 matrices) ----
    __shared__ unsigned short tl[64][73];
    int bx = blockIdx.x;
    int mat = bx >> 10;
    int tx = (bx >> 5) & 31, ty = bx & 31;
    const float* in; unsigned short* out; int perm;
    switch (mat) {
      case 0:  in = wq; out = wqkt;                       perm = 1; break;
      case 1:  in = wk; out = wqkt + (size_t)HID*HID;     perm = 1; break;
      case 2:  in = wv; out = wvt;                        perm = 0; break;
      default: in = wo; out = wot;                        perm = 0; break;
    }
    int n0 = tx * 64, k0 = ty * 64;
    int tid = threadIdx.x;
    int r = tid >> 3, c8 = (tid & 7) * 8;
    #pragma unroll
    for (int j = 0; j < 2; ++j) {
      int rr = r + j*32;
      const float* p = in + (size_t)(k0 + rr)*HID + n0 + c8;
      f32x4 v0 = *(const f32x4*)p;
      f32x4 v1 = *(const f32x4*)(p + 4);
      #pragma unroll
      for (int e = 0; e < 4; ++e) { tl[rr][c8 + e] = f2b(v0[e]); tl[rr][c8 + 4 + e] = f2b(v1[e]); }
    }
    __syncthreads();
    #pragma unroll
    for (int j = 0; j < 2; ++j) {
      int rr = r + j*32;
      int orow = n0 + rr;
      if (perm) {
        int s5 = (orow >> 5) & 3;
        s5 = (s5 == 1) ? 2 : (s5 == 2) ? 1 : s5;
        orow = (orow & ~127) | (s5 << 5) | (orow & 31);
      }
      short8 v;
      #pragma unroll
      for (int e = 0; e < 8; ++e) v[e] = (short)tl[c8 + e][rr];
      *(short8*)(out + (size_t)orow*HID + k0 + c8) = v;
    }
  }
}

// ============ shared GEMM helpers (swizzle proven: bank-conflict 0, rounds 2-18) ============

static __device__ __forceinline__ int swz_scol(int lane) {
  return (((lane & 7) * 16) ^ (((lane >> 3) & 7) << 4)) >> 1;   // swizzled src col (ushorts)
}

static __device__ __forceinline__ void rd_af(const unsigned short* Ah, bf16x8 (&afr)[4][2],
                                             int wm, int lr, int col0, int axor) {
  #pragma unroll
  for (int mi = 0; mi < 4; ++mi) {
    const unsigned short* rp = Ah + (wm*64 + mi*16 + lr) * 64;
    #pragma unroll
    for (int kk = 0; kk < 2; ++kk)
      afr[mi][kk] = *(const bf16x8*)(rp + (((kk*64 + col0) ^ axor) >> 1));
  }
}
static __device__ __forceinline__ void rd_bf(const unsigned short* Bh, bf16x8 (&bfr)[2][2],
                                             int wn, int lr, int col0, int axor) {
  #pragma unroll
  for (int ni = 0; ni < 2; ++ni) {
    const unsigned short* rp = Bh + (wn*32 + ni*16 + lr) * 64;
    #pragma unroll
    for (int kk = 0; kk < 2; ++kk)
      bfr[ni][kk] = *(const bf16x8*)(rp + (((kk*64 + col0) ^ axor) >> 1));
  }
}
static __device__ __forceinline__ void mfma16(const bf16x8 (&afr)[4][2], const bf16x8 (&bfr)[2][2],
                                              f32x4 (&ac)[4][2]) {
  #pragma unroll
  for (int kk = 0; kk < 2; ++kk)
    #pragma unroll
    for (int mi = 0; mi < 4; ++mi)
      #pragma unroll
      for (int ni = 0; ni < 2; ++ni)
        ac[mi][ni] = __builtin_amdgcn_mfma_f32_16x16x32_bf16(afr[mi][kk], bfr[ni][kk], ac[mi][ni], 0, 0, 0);
}

// ================= 128x256-tile GEMM, 3-deep pipeline (validated rounds 4-18; wo) =========

struct SPtrs { const unsigned short* p[6]; };

static __device__ __forceinline__ void build_ptrs(SPtrs& sp,
    const unsigned short* Ap, const unsigned short* Bp, int Ksz, int sh,
    int m0, int n0, const unsigned short* zpg, int tid) {
  int lane = tid & 63;
  int scol = swz_scol(lane);
  #pragma unroll
  for (int j = 0; j < 2; ++j) {
    int row = ((tid >> 6) * 2 + j) * 8 + (lane >> 3);               // 0..127
    int gr = m0 + row;
    sp.p[j]     = (sh && ((gr & (S - 1)) == 0)) ? (zpg + scol)
                                                : (Ap + (size_t)(gr - sh)*Ksz + scol);
    sp.p[2 + j] = Bp + (size_t)(n0 + row)*Ksz + scol;
    sp.p[4 + j] = Bp + (size_t)(n0 + 128 + row)*Ksz + scol;
  }
}

static __device__ __forceinline__ void stage6(unsigned short* buf, SPtrs& sp, int tid) {
  int c0 = (tid >> 6) * 1024;            // ushort offset of this wave's 2-chunk pair
  gload_lds16(sp.p[0], buf + c0);
  gload_lds16(sp.p[1], buf + c0 + 512);
  gload_lds16(sp.p[2], buf + 8192  + c0);
  gload_lds16(sp.p[3], buf + 8192  + c0 + 512);
  gload_lds16(sp.p[4], buf + 16384 + c0);
  gload_lds16(sp.p[5], buf + 16384 + c0 + 512);
  #pragma unroll
  for (int i = 0; i < 6; ++i) sp.p[i] += 64;
}

static __device__ __forceinline__ void gemm8_core(
    unsigned short* lds,
    const unsigned short* __restrict__ A1, const unsigned short* __restrict__ A2,
    const unsigned short* __restrict__ B1, const unsigned short* __restrict__ B2,
    int K1, int K2,
    const unsigned short* __restrict__ bias, const unsigned short* __restrict__ resid,
    void* __restrict__ Cout, int outmode, int N, int m0, int n0,
    int a1shift, const unsigned short* __restrict__ zrow) {
  int tid = threadIdx.x;
  int lane = tid & 63, w = tid >> 6;
  int wm = w >> 2, wn = w & 3;
  int lr = lane & 15, g = lane >> 4;
  int col0 = g * 16;
  int axor = (lr & 7) << 4;
  int nk1 = K1 >> 6;
  int nk = (K1 + K2) >> 6;
  f32x4 acc[2][4][2] = {};
  bf16x8 afr[4][2], bfr0[2][2], bfr1[2][2];

  unsigned short* buf0 = lds;            // each buf: A @0, B0 @8192, B1 @16384 (ushorts)
  unsigned short* buf1 = lds + 24576;
  unsigned short* buf2 = lds + 49152;

  SPtrs sp;
  build_ptrs(sp, A1, B1, K1, a1shift, m0, n0, zrow, tid);

  stage6(buf0, sp, tid);
  stage6(buf1, sp, tid);

  unsigned short* cur = buf0;
  unsigned short* nx1 = buf1;
  unsigned short* nx2 = buf2;
  for (int t = 0; t < nk; ++t) {
    if (t < nk - 1) asm volatile("s_waitcnt vmcnt(6)" ::: "memory");
    else            asm volatile("s_waitcnt vmcnt(0)" ::: "memory");
    __builtin_amdgcn_s_barrier();
    asm volatile("" ::: "memory");

    rd_af(cur,         afr,  wm, lr, col0, axor);
    rd_bf(cur + 8192,  bfr0, wn, lr, col0, axor);
    rd_bf(cur + 16384, bfr1, wn, lr, col0, axor);
    if (t + 2 < nk) {
      if (t + 2 == nk1) build_ptrs(sp, A2, B2, K2, 0, m0, n0, zrow, tid);
      stage6(nx2, sp, tid);
    }
    __builtin_amdgcn_s_setprio(1);
    mfma16(afr, bfr0, acc[0]);
    mfma16(afr, bfr1, acc[1]);
    __builtin_amdgcn_s_setprio(0);

    unsigned short* tmp = cur; cur = nx1; nx1 = nx2; nx2 = tmp;
  }

  #pragma unroll
  for (int qn = 0; qn < 2; ++qn)
    #pragma unroll
    for (int mi = 0; mi < 4; ++mi) {
      int row0 = m0 + wm*64 + mi*16 + g*4;
      #pragma unroll
      for (int ni = 0; ni < 2; ++ni) {
        int col = n0 + qn*128 + wn*32 + ni*16 + lr;
        float bv = bias ? b2f(bias[col]) : 0.f;
        f32x4 a = acc[qn][mi][ni];
        #pragma unroll
        for (int j = 0; j < 4; ++j) {
          size_t idx = (size_t)(row0 + j) * N + col;
          float v = a[j] + bv;
          if (resid) v += b2f(resid[idx]);
          if (outmode == 1) ((float*)Cout)[idx] = v;
          else ((unsigned short*)Cout)[idx] = f2b(v);
        }
      }
    }
}

template<int SHIFT>
__launch_bounds__(512, 1)
__global__ void gemm8_bt(const unsigned short* __restrict__ A1,
                         const unsigned short* __restrict__ A2,
                         const unsigned short* __restrict__ B1,
                         const unsigned short* __restrict__ B2,
                         int K1, int K2,
                         const unsigned short* __restrict__ bias,
                         const unsigned short* __restrict__ resid,
                         void* __restrict__ Cout, int outmode, int N,
                         const unsigned short* __restrict__ zrow) {
  __shared__ __align__(16) unsigned short lds[73728];   // 144 KiB, 3 bufs
  gemm8_core(lds, A1, A2, B1, B2, K1, K2, bias, resid, Cout, outmode, N,
             blockIdx.x*128, blockIdx.y*256, SHIFT, zrow);
}

// ============ 256x256-tile 4-phase core (validated rounds 12-18) ============
struct HPtr { const unsigned short* p0; const unsigned short* p1; };
static __device__ __forceinline__ void hinit(HPtr& h, const unsigned short* base,
                                             int row0, int Ksz, int tid) {
  int lane = tid & 63;
  int scol = swz_scol(lane);
  int r0 = ((tid >> 6) * 2) * 8 + (lane >> 3);
  h.p0 = base + (size_t)(row0 + r0) * Ksz + scol;
  h.p1 = base + (size_t)(row0 + r0 + 8) * Ksz + scol;
}
// shifted variant: reads row-1 (zero page at batch starts); zpg reads advance with kk
static __device__ __forceinline__ void hinit_sh(HPtr& h, const unsigned short* base,
                                                int row0, int Ksz,
                                                const unsigned short* zpg, int tid) {
  int lane = tid & 63;
  int scol = swz_scol(lane);
  int r0 = ((tid >> 6) * 2) * 8 + (lane >> 3);
  int g0 = row0 + r0, g1 = row0 + r0 + 8;
  h.p0 = ((g0 & (S - 1)) == 0) ? (zpg + scol) : (base + (size_t)(g0 - 1) * Ksz + scol);
  h.p1 = ((g1 & (S - 1)) == 0) ? (zpg + scol) : (base + (size_t)(g1 - 1) * Ksz + scol);
}
static __device__ __forceinline__ void hstage(unsigned short* slot, HPtr& h, int tid) {
  int c0 = (tid >> 6) * 1024;
  gload_lds16(h.p0, slot + c0);
  gload_lds16(h.p1, slot + c0 + 512);
  h.p0 += 64; h.p1 += 64;
}

// core K-loop (NKT 64-wide K-tiles), shared by qk / trio / duo
template<int NKT>
static __device__ __forceinline__ void gemm256_loop(
    unsigned short* lds, HPtr& hA0, HPtr& hA1, HPtr& hB0, HPtr& hB1,
    f32x4 (&acc)[2][2][4][2], int wm, int wn, int lr, int col0, int axor, int tid) {
  bf16x8 af[4][2], bf0[2][2], bf1[2][2];
  const int nk = NKT;
  // prologue: tile0 {A0,A1,B0,B1} -> buf0 ; tile1 {A0,B0,B1} -> buf1
  hstage(lds + 0,             hA0, tid);
  hstage(lds + 8192,          hA1, tid);
  hstage(lds + 16384,         hB0, tid);
  hstage(lds + 24576,         hB1, tid);
  hstage(lds + 32768 + 0,     hA0, tid);
  hstage(lds + 32768 + 16384, hB0, tid);
  hstage(lds + 32768 + 24576, hB1, tid);
  asm volatile("s_waitcnt vmcnt(6)" ::: "memory");   // tile0 landed; tile1's 3 halves in flight
  __builtin_amdgcn_s_barrier();
  asm volatile("" ::: "memory");

  for (int t = 0; t < nk; ++t) {
    unsigned short* cur = lds + (t & 1) * 32768;
    unsigned short* oth = lds + ((t & 1) ^ 1) * 32768;

    // ---- P1 (qm0,qn0): rd A0(8)+B0(4) ; stage A1(t+1) -> oth ----
    rd_af(cur,         af,  wm, lr, col0, axor);
    rd_bf(cur + 16384, bf0, wn, lr, col0, axor);
    if (t + 1 < nk) hstage(oth + 8192, hA1, tid);
    __builtin_amdgcn_s_barrier();
    asm volatile("s_waitcnt lgkmcnt(0)" ::: "memory");
    __builtin_amdgcn_s_setprio(1);
    mfma16(af, bf0, acc[0][0]);
    __builtin_amdgcn_s_setprio(0);
    __builtin_amdgcn_s_barrier();

    // ---- P2 (qm0,qn1): rd B1(4) (A regs reused) ; stage A0(t+2) -> cur ----
    rd_bf(cur + 24576, bf1, wn, lr, col0, axor);
    if (t + 2 < nk) hstage(cur, hA0, tid);
    __builtin_amdgcn_s_barrier();
    asm volatile("s_waitcnt lgkmcnt(0)" ::: "memory");
    __builtin_amdgcn_s_setprio(1);
    mfma16(af, bf1, acc[0][1]);
    __builtin_amdgcn_s_setprio(0);
    __builtin_amdgcn_s_barrier();

    // ---- P3 (qm1,qn1): rd A1(8) (B1 regs reused) ; stage B0(t+2) -> cur ----
    rd_af(cur + 8192, af, wm, lr, col0, axor);
    if (t + 2 < nk) hstage(cur + 16384, hB0, tid);
    __builtin_amdgcn_s_barrier();
    asm volatile("s_waitcnt lgkmcnt(0)" ::: "memory");
    __builtin_amdgcn_s_setprio(1);
    mfma16(af, bf1, acc[1][1]);
    __builtin_amdgcn_s_setprio(0);
    __builtin_amdgcn_s_barrier();

    // ---- P4 (qm1,qn0): all regs reused ; stage B1(t+2) -> cur ; counted vmcnt ----
    if (t + 2 < nk) hstage(cur + 24576, hB1, tid);
    __builtin_amdgcn_s_barrier();
    asm volatile("s_waitcnt lgkmcnt(0)" ::: "memory");
    __builtin_amdgcn_s_setprio(1);
    mfma16(af, bf0, acc[1][0]);
    __builtin_amdgcn_s_setprio(0);
    if (t + 2 < nk) asm volatile("s_waitcnt vmcnt(6)" ::: "memory");
    else            asm volatile("s_waitcnt vmcnt(0)" ::: "memory");
    __builtin_amdgcn_s_barrier();
    asm volatile("" ::: "memory");
  }
}

// ---- qk projection + FUSED RoPE (validated rounds 17-18) ----
__launch_bounds__(512, 1)
__global__ void gemm256_qk_rope(const unsigned short* __restrict__ A,
                                const unsigned short* __restrict__ B,
                                const float* __restrict__ ctab,
                                const float* __restrict__ stab,
                                unsigned short* __restrict__ qr,
                                unsigned short* __restrict__ kr) {
  __shared__ __align__(16) unsigned short lds[65536];   // 128 KiB
  int tid = threadIdx.x;
  int lane = tid & 63, w = tid >> 6;
  int wm = w >> 2, wn = w & 3;
  int lr = lane & 15, g = lane >> 4;
  int col0 = g * 16;
  int axor = (lr & 7) << 4;
  int nwg = gridDim.x * gridDim.y;
  int lin = blockIdx.y * gridDim.x + blockIdx.x;
  int cpx = nwg >> 3;
  int swz = (lin & 7) * cpx + (lin >> 3);
  int m0 = (swz % gridDim.x) * 256, n0 = (swz / gridDim.x) * 256;
  f32x4 acc[2][2][4][2] = {};           // [qm][qn][mi][ni]

  HPtr hA0, hA1, hB0, hB1;
  hinit(hA0, A, m0,       2048, tid);
  hinit(hA1, A, m0 + 128, 2048, tid);
  hinit(hB0, B, n0,       2048, tid);
  hinit(hB1, B, n0 + 128, 2048, tid);
  gemm256_loop<32>(lds, hA0, hA1, hB0, hB1, acc, wm, wn, lr, col0, axor, tid);

  // ---- fused RoPE epilogue ----
  float* L = (float*)lds;                // [128][132] f32 = 67.6KB
  const float SC = 0.08838834764831845f * 1.44269504088896340f;  // 1/sqrt(128) * log2(e)
  int h = n0 >> 8;
  int r2 = tid >> 2;                     // 0..127
  int ib = (tid & 3) * 16;               // i block 0/16/32/48
  #pragma unroll
  for (int qm = 0; qm < 2; ++qm) {
    #pragma unroll
    for (int qn = 0; qn < 2; ++qn) {
      #pragma unroll
      for (int mi = 0; mi < 4; ++mi)
        #pragma unroll
        for (int ni = 0; ni < 2; ++ni) {
          f32x4 a = acc[qm][qn][mi][ni];
          #pragma unroll
          for (int j = 0; j < 4; ++j)
            L[(wm*64 + mi*16 + g*4 + j)*132 + wn*32 + ni*16 + lr] = a[j];
        }
      __syncthreads();
      int rowg = m0 + qm*128 + r2;
      int t = rowg & (S - 1);
      size_t o = (size_t)rowg * HID + (size_t)h * HD;
      unsigned short* dst = (qn == 0) ? qr : kr;
      float sc = (qn == 0) ? SC : 1.0f;
      #pragma unroll
      for (int v4 = 0; v4 < 4; ++v4) {
        ushort4v w1, w2;
        #pragma unroll
        for (int e = 0; e < 4; ++e) {
          int i = ib + v4*4 + e;
          int pc = (i & 31) + ((i >> 5) << 6);
          float x1 = L[r2*132 + pc];
          float x2 = L[r2*132 + pc + 32];
          float cc = ctab[t*64 + i];
          float sn = stab[t*64 + i];
          w1[e] = f2b((x1*cc - x2*sn) * sc);
          w2[e] = f2b((x2*cc + x1*sn) * sc);
        }
        *(ushort4v*)(dst + o + ib + v4*4)      = w1;
        *(ushort4v*)(dst + o + 64 + ib + v4*4) = w2;
      }
      __syncthreads();
    }
  }
}

// ---- trio: conv1-pieceA (shifted) + conv1-pieceB + V-proj, uniform K=2048 ----
// (validated round 18: Vt epilogue via LDS transpose + s-coalesced writes)
__launch_bounds__(512, 1)
__global__ void gemm256_trio(const unsigned short* __restrict__ xb,
                             const unsigned short* __restrict__ w1t0,
                             const unsigned short* __restrict__ w1t1,
                             const unsigned short* __restrict__ wvt,
                             unsigned short* __restrict__ o1a,
                             unsigned short* __restrict__ o1b,
                             unsigned short* __restrict__ vtg,
                             const unsigned short* __restrict__ zpg) {
  __shared__ __align__(16) unsigned short lds[68608];
  int tid = threadIdx.x;
  int lane = tid & 63, w = tid >> 6;
  int wm = w >> 2, wn = w & 3;
  int lr = lane & 15, g = lane >> 4;
  int col0 = g * 16;
  int axor = (lr & 7) << 4;
  int lin = blockIdx.x;
  int swz = (lin & 7) * 32 + (lin >> 3);
  int job, s;
  if (swz < 64)       { job = 0; s = swz; }
  else if (swz < 128) { job = 1; s = swz - 64; }
  else                { job = 2; s = swz - 128; }
  int m0 = (s & 15) * 256;
  int n0 = (s >> 4) * 256;
  f32x4 acc[2][2][4][2] = {};

  HPtr hA0, hA1, hB0, hB1;
  if (job == 0) { hinit_sh(hA0, xb, m0, 2048, zpg, tid); hinit_sh(hA1, xb, m0 + 128, 2048, zpg, tid); }
  else          { hinit(hA0, xb, m0, 2048, tid);         hinit(hA1, xb, m0 + 128, 2048, tid); }
  const unsigned short* B = (job == 0) ? w1t0 : (job == 1) ? w1t1 : wvt;
  hinit(hB0, B, n0,       2048, tid);
  hinit(hB1, B, n0 + 128, 2048, tid);
  gemm256_loop<32>(lds, hA0, hA1, hB0, hB1, acc, wm, wn, lr, col0, axor, tid);

  if (job < 2) {
    unsigned short* C = (job == 0) ? o1a : o1b;   // bf16 [4096][1024] partial
    #pragma unroll
    for (int qm = 0; qm < 2; ++qm)
      #pragma unroll
      for (int mi = 0; mi < 4; ++mi) {
        int row0 = m0 + qm*128 + wm*64 + mi*16 + g*4;
        #pragma unroll
        for (int qn = 0; qn < 2; ++qn)
          #pragma unroll
          for (int ni = 0; ni < 2; ++ni) {
            int col = n0 + qn*128 + wn*32 + ni*16 + lr;
            f32x4 a = acc[qm][qn][mi][ni];
            #pragma unroll
            for (int j = 0; j < 4; ++j)
              C[(size_t)(row0 + j) * 1024 + col] = f2b(a[j]);
          }
      }
  } else {
    // ---- Vt epilogue: LDS transpose -> s-coalesced writes ----
    float* L = (float*)lds;               // [128][133] f32
    #pragma unroll
    for (int qm = 0; qm < 2; ++qm) {
      #pragma unroll
      for (int qn = 0; qn < 2; ++qn) {
        #pragma unroll
        for (int mi = 0; mi < 4; ++mi)
          #pragma unroll
          for (int ni = 0; ni < 2; ++ni) {
            f32x4 a = acc[qm][qn][mi][ni];
            #pragma unroll
            for (int j = 0; j < 4; ++j)
              L[(wm*64 + mi*16 + g*4 + j)*133 + wn*32 + ni*16 + lr] = a[j];
          }
        __syncthreads();
        int rowg0 = m0 + qm*128;          // quadrant s base (never straddles batch)
        int bb = rowg0 >> 11;
        int s0q = rowg0 & (S - 1);
        int dg0 = n0 + qn*128;            // quadrant d base
        #pragma unroll
        for (int cl = 0; cl < 16; ++cl) {
          int col = w*16 + cl;
          size_t vbase = ((size_t)bb * HID + dg0 + col) * S + s0q;
          vtg[vbase + lane]      = f2b(L[lane*133 + col]);
          vtg[vbase + 64 + lane] = f2b(L[(64 + lane)*133 + col]);
        }
        __syncthreads();
      }
    }
  }
}

// ---- duo: conv2-pieceA (shifted o1 @ W2_0) + conv2-pieceB (o1 @ W2_1), uniform K=1024 ----
__launch_bounds__(512, 1)
__global__ void gemm256_duo(const unsigned short* __restrict__ o1,
                            const unsigned short* __restrict__ w2t0,
                            const unsigned short* __restrict__ w2t1,
                            unsigned short* __restrict__ pA,
                            unsigned short* __restrict__ pB,
                            const unsigned short* __restrict__ zpg) {
  __shared__ __align__(16) unsigned short lds[65536];   // 128 KiB
  int tid = threadIdx.x;
  int lane = tid & 63, w = tid >> 6;
  int wm = w >> 2, wn = w & 3;
  int lr = lane & 15, g = lane >> 4;
  int col0 = g * 16;
  int axor = (lr & 7) << 4;
  int lin = blockIdx.x;
  int swz = (lin & 7) * 32 + (lin >> 3);
  int job = swz >> 7;                 // 0: shifted @ W2_0 ; 1: direct @ W2_1
  int s = swz & 127;
  int m0 = (s & 15) * 256;            // 16 M-tiles
  int n0 = (s >> 4) * 256;            // 8 N-tiles
  f32x4 acc[2][2][4][2] = {};

  HPtr hA0, hA1, hB0, hB1;
  if (job == 0) { hinit_sh(hA0, o1, m0, 1024, zpg, tid); hinit_sh(hA1, o1, m0 + 128, 1024, zpg, tid); }
  else          { hinit(hA0, o1, m0, 1024, tid);         hinit(hA1, o1, m0 + 128, 1024, tid); }
  const unsigned short* B = (job == 0) ? w2t0 : w2t1;
  hinit(hB0, B, n0,       1024, tid);
  hinit(hB1, B, n0 + 128, 1024, tid);
  gemm256_loop<16>(lds, hA0, hA1, hB0, hB1, acc, wm, wn, lr, col0, axor, tid);

  unsigned short* C = (job == 0) ? pA : pB;       // bf16 [4096][2048] partial
  #pragma unroll
  for (int qm = 0; qm < 2; ++qm)
    #pragma unroll
    for (int mi = 0; mi < 4; ++mi) {
      int row0 = m0 + qm*128 + wm*64 + mi*16 + g*4;
      #pragma unroll
      for (int qn = 0; qn < 2; ++qn)
        #pragma unroll
        for (int ni = 0; ni < 2; ++ni) {
          int col = n0 + qn*128 + wn*32 + ni*16 + lr;
          f32x4 a = acc[qm][qn][mi][ni];
          #pragma unroll
          for (int j = 0; j < 4; ++j)
            C[(size_t)(row0 + j) * HID + col] = f2b(a[j]);
        }
    }
}

// ---- o1 = o1a + o1b + bias (bf16, 4096x1024) ----
__global__ void add_bias(const unsigned short* __restrict__ a,
                         const unsigned short* __restrict__ b,
                         const unsigned short* __restrict__ bias,
                         unsigned short* __restrict__ o) {
  long i8 = ((long)blockIdx.x * 256 + threadIdx.x) * 8;   // over 4096*1024
  short8 va = *(const short8*)(a + i8);
  short8 vb = *(const short8*)(b + i8);
  short8 wb = *(const short8*)(bias + (i8 & 1023));
  short8 vo;
  #pragma unroll
  for (int e = 0; e < 8; ++e)
    vo[e] = (short)f2b(b2f((unsigned short)va[e]) + b2f((unsigned short)vb[e])
                       + b2f((unsigned short)wb[e]));
  *(short8*)(o + i8) = vo;
}

// ---- fused: hg = rmsnorm(pA + pB + bias + resid) * w ----
__global__ void rms_fuse(const unsigned short* __restrict__ pA,
                         const unsigned short* __restrict__ pB,
                         const unsigned short* __restrict__ bias,
                         const unsigned short* __restrict__ resid,
                         const unsigned short* __restrict__ w,
                         unsigned short* __restrict__ out) {
  int r = blockIdx.x;
  int c8 = threadIdx.x * 8;               // 256 threads x 8 = 2048
  size_t base = (size_t)r * HID + c8;
  short8 va = *(const short8*)(pA + base);
  short8 vb = *(const short8*)(pB + base);
  short8 vx = *(const short8*)(resid + base);
  short8 vbi = *(const short8*)(bias + c8);
  float f[8];
  float ss = 0.f;
  #pragma unroll
  for (int e = 0; e < 8; ++e) {
    f[e] = b2f((unsigned short)va[e]) + b2f((unsigned short)vb[e])
         + b2f((unsigned short)vbi[e]) + b2f((unsigned short)vx[e]);
    ss += f[e]*f[e];
  }
  #pragma unroll
  for (int o = 32; o; o >>= 1) ss += __shfl_xor(ss, o);
  __shared__ float red[4];
  if ((threadIdx.x & 63) == 0) red[threadIdx.x >> 6] = ss;
  __syncthreads();
  float tot = red[0] + red[1] + red[2] + red[3];
  float scale = rsqrtf(tot / (float)HID + 1e-6f);
  short8 wv = *(const short8*)(w + c8);
  short8 o8;
  #pragma unroll
  for (int e = 0; e < 8; ++e) o8[e] = (short)f2b(f[e] * scale * b2f((unsigned short)wv[e]));
  *(short8*)(out + base) = o8;
}

// ---------------- MFMA causal flash attention (16x16, DMA-staged, balanced pairs) ----------------
#define KT 64

static __device__ __forceinline__ void attn_pass(
    int qt, int b, int h, unsigned short* lds,
    const unsigned short* __restrict__ Qr, const unsigned short* __restrict__ Kr,
    const unsigned short* __restrict__ Vt, unsigned short* __restrict__ Out) {
  int tid = threadIdx.x, lane = tid & 63, w = tid >> 6;
  int q0 = qt * 64;
  size_t bS = (size_t)b * S;
  size_t ho = (size_t)h * HD;
  int lr = lane & 15, g = lane >> 4;
  int rsw = (lane & 7) << 3;                       // read-side swizzle (ushort units)
  // all waves past previous pass's LDS reads before re-staging the shared buffers
  __syncthreads();
  bf16x8 bq[4];
  {
    int qrow = q0 + w*16 + lr;
    const unsigned short* qp = Qr + (bS + qrow)*HID + ho + g*8;
    #pragma unroll
    for (int kk = 0; kk < 4; ++kk) bq[kk] = *(const bf16x8*)(qp + kk*32);
  }
  // staging pointers (pre-swizzled source cols; advance per tile)
  const unsigned short* kp[4];
  const unsigned short* vp[4];
  #pragma unroll
  for (int j = 0; j < 4; ++j) {
    int c = w*4 + j;                       // chunk 0..15 (1KB each)
    int rk = c*4 + (lane >> 4);            // K row 0..63
    int sck = ((lane & 15) * 8) ^ ((rk & 7) << 3);
    kp[j] = Kr + (bS + rk)*HID + ho + sck;
    int rv = c*8 + (lane >> 3);            // V row (d) 0..127
    int scv = ((lane & 7) * 8) ^ ((rv & 7) << 3);
    vp[j] = Vt + ((size_t)b*HID + ho + rv)*S + scv;
  }
  int cdst = (w*4) * 512;                  // this wave's chunk-group dest (ushorts)
  unsigned short* curK = lds;
  unsigned short* curV = lds + 8192;
  unsigned short* nxtK = lds + 16384;
  unsigned short* nxtV = lds + 24576;
  #pragma unroll
  for (int j = 0; j < 4; ++j) {            // prologue: tile 0 -> cur
    gload_lds16(kp[j], curK + cdst + j*512);
    gload_lds16(vp[j], curV + cdst + j*512);
    kp[j] += (size_t)KT * HID;
    vp[j] += KT;
  }
  f32x4 o[8] = {};                 // O: col(d)=lr+16*ni, row(q_local)=4g+reg
  float m = -1e30f, l = 0.f;
  unsigned short* PlW = lds + 32768 + w*1024;
  int ntiles = qt + 1;
  for (int kt = 0; kt < ntiles; ++kt) {
    // ---- single sync point: own DMA landed, then block-wide barrier ----
    asm volatile("s_waitcnt vmcnt(0)" ::: "memory");
    __builtin_amdgcn_s_barrier();
    asm volatile("" ::: "memory");
    if (kt + 1 < ntiles) {                 // issue next-tile DMA into the other buffer
      #pragma unroll
      for (int j = 0; j < 4; ++j) {
        gload_lds16(kp[j], nxtK + cdst + j*512);
        gload_lds16(vp[j], nxtV + cdst + j*512);
        kp[j] += (size_t)KT * HID;
        vp[j] += KT;
      }
    }
    f32x4 st[4] = {};
    __builtin_amdgcn_s_setprio(1);
    #pragma unroll
    for (int kk = 0; kk < 4; ++kk) {
      #pragma unroll
      for (int mi = 0; mi < 4; ++mi) {
        bf16x8 a = *(const bf16x8*)(&curK[(mi*16 + lr)*128 + ((kk*32 + g*8) ^ rsw)]);
        st[mi] = __builtin_amdgcn_mfma_f32_16x16x32_bf16(a, bq[kk], st[mi], 0, 0, 0);
      }
    }
    __builtin_amdgcn_s_setprio(0);
    bool lastt = (kt == ntiles - 1);
    float tm = -1e30f;
    #pragma unroll
    for (int mi = 0; mi < 4; ++mi)
      #pragma unroll
      for (int r = 0; r < 4; ++r) {
        float v = st[mi][r];
        if (lastt && (mi*16 + 4*g + r) > (w*16 + lr)) v = -1e30f;
        st[mi][r] = v;
        tm = fmaxf(tm, v);
      }
    tm = fmaxf(tm, __shfl_xor(tm, 16));
    tm = fmaxf(tm, __shfl_xor(tm, 32));
    if (!__all(tm - m <= 11.5f)) {
      float mn = fmaxf(m, tm);
      float sc = exp2f(m - mn);
      float s0 = __shfl(sc, 4*g+0), s1 = __shfl(sc, 4*g+1);
      float s2 = __shfl(sc, 4*g+2), s3 = __shfl(sc, 4*g+3);
      #pragma unroll
      for (int ni = 0; ni < 8; ++ni) {
        o[ni][0] *= s0; o[ni][1] *= s1; o[ni][2] *= s2; o[ni][3] *= s3;
      }
      l *= sc;
      m = mn;
    }
    float ts = 0.f;
    __bf16 pbf[4][4];
    #pragma unroll
    for (int mi = 0; mi < 4; ++mi)
      #pragma unroll
      for (int r = 0; r < 4; ++r) {
        float p = exp2f(st[mi][r] - m);
        ts += p;
        pbf[mi][r] = (__bf16)p;
      }
    ts += __shfl_xor(ts, 16);
    ts += __shfl_xor(ts, 32);
    l += ts;
    #pragma unroll
    for (int mi = 0; mi < 4; ++mi) {
      bf16x4 pk = { pbf[mi][0], pbf[mi][1], pbf[mi][2], pbf[mi][3] };
      *(bf16x4*)(&PlW[lr*64 + ((mi*16 + 4*g) ^ rsw)]) = pk;
    }
    asm volatile("" ::: "memory");   // compile-time fence: P stores before P reads
    __builtin_amdgcn_s_setprio(1);
    #pragma unroll
    for (int kk = 0; kk < 2; ++kk) {
      int pc = (kk*32 + g*8) ^ rsw;
      bf16x8 a = *(const bf16x8*)(&PlW[lr*64 + pc]);
      #pragma unroll
      for (int ni = 0; ni < 8; ++ni) {
        bf16x8 bv = *(const bf16x8*)(&curV[(ni*16 + lr)*64 + pc]);
        o[ni] = __builtin_amdgcn_mfma_f32_16x16x32_bf16(a, bv, o[ni], 0, 0, 0);
      }
    }
    __builtin_amdgcn_s_setprio(0);
    unsigned short* t0 = curK; curK = nxtK; nxtK = t0;
    unsigned short* t1 = curV; curV = nxtV; nxtV = t1;
  }
  float l0 = __shfl(l, 4*g+0), l1 = __shfl(l, 4*g+1);
  float l2 = __shfl(l, 4*g+2), l3 = __shfl(l, 4*g+3);
  float i0 = 1.f/l0, i1 = 1.f/l1, i2 = 1.f/l2, i3 = 1.f/l3;
  int rbase = q0 + w*16 + 4*g;
  #pragma unroll
  for (int ni = 0; ni < 8; ++ni) {
    size_t cbase = ho + ni*16 + lr;
    Out[(bS + rbase + 0)*HID + cbase] = f2b(o[ni][0]*i0);
    Out[(bS + rbase + 1)*HID + cbase] = f2b(o[ni][1]*i1);
    Out[(bS + rbase + 2)*HID + cbase] = f2b(o[ni][2]*i2);
    Out[(bS + rbase + 3)*HID + cbase] = f2b(o[ni][3]*i3);
  }
}

__launch_bounds__(256, 2)
__global__ void attn_mfma(const unsigned short* __restrict__ Qr,
                          const unsigned short* __restrict__ Kr,
                          const unsigned short* __restrict__ Vt,
                          unsigned short* __restrict__ Out) {
  // [0,8192) K0 | [8192,16384) V0 | [16384,24576) K1 | [24576,32768) V1 | [32768,36864) P
  __shared__ __align__(16) unsigned short lds[36864];
  int bh = blockIdx.x;
  int b = bh >> 4, h = bh & 15;
  int by = blockIdx.y;                       // 0..15
  attn_pass(31 - by, b, h, lds, Qr, Kr, Vt, Out);   // heavy tile
  attn_pass(by,      b, h, lds, Qr, Kr, Vt, Out);   // light tile; total = 33 KV-tiles/block
}

extern "C" void kernel_launch(void* const* d_in, const int* in_sizes, int n_in,
                              void* d_out, int out_size, void* d_ws, size_t ws_size,
                              hipStream_t stream) {
  const float* x_raw   = (const float*)d_in[0];
  const int* positions = (const int*)d_in[1];
  const float* wq_raw  = (const float*)d_in[2];
  const float* wk_raw  = (const float*)d_in[3];
  const float* wv_raw  = (const float*)d_in[4];
  const float* wo_raw  = (const float*)d_in[5];
  const float* c1w_raw = (const float*)d_in[6];
  const float* c1b_raw = (const float*)d_in[7];
  const float* c2w_raw = (const float*)d_in[8];
  const float* c2b_raw = (const float*)d_in[9];
  const float* rms_raw = (const float*)d_in[10];

  const size_t WS_NEEDED = 140000000;
  if (ws_size < WS_NEEDED) {
    long n = (long)out_size;
    fill_debug<<<dim3((unsigned)((n + 255) / 256)), dim3(256), 0, stream>>>((unsigned short*)d_out, n);
    return;
  }

  char* ws = (char*)d_ws;
  size_t off = 0;
  auto alloc = [&](size_t bytes) { char* p = ws + off; off += (bytes + 255) & ~(size_t)255; return p; };
  float* ctab          = (float*)alloc((size_t)S*64*4);
  float* stab          = (float*)alloc((size_t)S*64*4);
  unsigned short* wqkt = (unsigned short*)alloc((size_t)2*HID*HID*2);  // [wq^T ; wk^T], rope-permuted
  unsigned short* wvt  = (unsigned short*)alloc((size_t)HID*HID*2);
  unsigned short* wot  = (unsigned short*)alloc((size_t)HID*HID*2);
  unsigned short* w1t0 = (unsigned short*)alloc((size_t)1024*HID*2);
  unsigned short* w1t1 = (unsigned short*)alloc((size_t)1024*HID*2);
  unsigned short* w2t0 = (unsigned short*)alloc((size_t)HID*1024*2);
  unsigned short* w2t1 = (unsigned short*)alloc((size_t)HID*1024*2);
  unsigned short* xb   = (unsigned short*)alloc((size_t)ROWS*HID*2);   // resid for rms_fuse; reused as kr
  unsigned short* qrb  = (unsigned short*)alloc((size_t)ROWS*HID*2);   // q rotated
  unsigned short* o1   = (unsigned short*)alloc((size_t)ROWS*1024*2);
  unsigned short* yb   = (unsigned short*)alloc((size_t)ROWS*HID*2);   // attn out buffer
  unsigned short* hg   = (unsigned short*)alloc((size_t)ROWS*HID*2);
  unsigned short* qkf  = (unsigned short*)alloc((size_t)ROWS*2*HID*2); // partial scratch (trio/duo)
  unsigned short* vtg  = (unsigned short*)alloc((size_t)BATCH*HID*S*2);
  unsigned short* c1bb = (unsigned short*)alloc(1024*2);
  unsigned short* c2bb = (unsigned short*)alloc(2048*2);
  unsigned short* rmswb= (unsigned short*)alloc(2048*2);
  unsigned short* zpg  = (unsigned short*)alloc(8192*2);               // zero page (kk-advancing)
  unsigned short* krr  = xb;     // xb dead after rms_fuse (resid read)
  unsigned short* attn = yb;
  unsigned short* o1a  = qkf;                              // conv1 partials in qkf scratch
  unsigned short* o1b  = qkf + (size_t)ROWS*1024;
  unsigned short* cpA  = qkf;                              // conv2 partials (after add_bias)
  unsigned short* cpB  = qkf + (size_t)ROWS*HID;

  dim3 b256(256);
  dim3 b512(512);
  // merged prep: converts + rope tables + all 4 weight transposes in ONE dispatch
  prep_combined<<<dim3(4096, 5), b256, 0, stream>>>(
      c1w_raw, c2w_raw, x_raw, positions, c1b_raw, c2b_raw, rms_raw,
      wq_raw, wk_raw, wv_raw, wo_raw,
      w1t0, w1t1, w2t0, w2t1, xb, ctab, stab, c1bb, c2bb, rmswb, zpg,
      wqkt, wvt, wot);
  // trio (256^2 4-phase, 256 uniform K=2048 blocks): conv1-pieceA/B partials + V-proj
  gemm256_trio<<<dim3(256), b512, 0, stream>>>(xb, w1t0, w1t1, wvt, o1a, o1b, vtg, zpg);
  // o1 = o1a + o1b + bias
  add_bias<<<dim3(ROWS*1024/8/256), b256, 0, stream>>>(o1a, o1b, c1bb, o1);
  // duo (256^2 4-phase, 256 uniform K=1024 blocks): conv2 partials
  gemm256_duo<<<dim3(256), b512, 0, stream>>>(o1, w2t0, w2t1, cpA, cpB, zpg);
  // fused: hg = rmsnorm(pA + pB + b2 + xb) * rmsw
  rms_fuse<<<dim3(ROWS), b256, 0, stream>>>(cpA, cpB, c2bb, xb, rmswb, hg);
  // fused q|k projection + RoPE (256x256 4-phase + XCD swizzle): qrb/krr directly
  gemm256_qk_rope<<<dim3(ROWS/256, (2*HID)/256), b512, 0, stream>>>(hg, wqkt, ctab, stab, qrb, krr);
  attn_mfma<<<dim3(BATCH*HEADS, 16), b256, 0, stream>>>(qrb, krr, vtg, attn);
  // output projection: d_out = attn @ wo^T   [4096 x 2048], f32 out
  gemm8_bt<0><<<dim3(ROWS/128, HID/256), b512, 0, stream>>>(attn, attn, wot, wot, HID, 0, nullptr, nullptr, d_out, 1, HID, nullptr);
}